// Round 1
// baseline (9252.846 us; speedup 1.0000x reference)
//
#include <hip/hip_runtime.h>

// RNN: B=32, T=2048, E=256, H=256, L=2, f32.
// z_l = concat([inp, h_l]) @ W_l + b_l ; h_l = tanh(z_l)
// Strategy:
//   A: xproj0 = x @ W0[0:256] + b0            -> d_out (staging)
//   B: layer-0 scan in-place on d_out          (row t: read xproj0, write h0_t)
//   C: xproj1 = h0_all @ W1[0:256] + b1        (in-place on d_out, LDS-staged rows)
//   D: layer-1 scan in-place on d_out          -> hidden_states; tail: ht final
// Scan: 1 WG per batch row, 1024 thr, thread (c=tid&3, j=tid>>2) holds
// Wh[64c..64c+64, j] in 64 VGPRs; h double-buffered in LDS; shfl_xor(1,2)
// reduce; 1 barrier/step.

#define TT 2048
#define BB 32
#define HHH 256

__global__ __launch_bounds__(1024) void proj_kernel(
    const float* __restrict__ in,    // [R,256]
    const float* __restrict__ W,     // [512,256]; uses rows [wrow, wrow+256)
    const float* __restrict__ bias,  // [256]
    float* __restrict__ out,         // [R,256] (may alias `in`)
    int rows_per_wg, int wrow)
{
    __shared__ float row[256];
    const int tid = threadIdx.x;
    const int c = tid & 3;
    const int j = tid >> 2;

    // per-thread weight column chunk: W[wrow + 64c + i][j], i=0..63
    float w[64];
#pragma unroll
    for (int i = 0; i < 64; ++i)
        w[i] = W[(size_t)(wrow + c * 64 + i) * 256 + j];
    const float bj = bias[j];

    const size_t r0 = (size_t)blockIdx.x * rows_per_wg;
    for (int rr = 0; rr < rows_per_wg; ++rr) {
        const size_t r = r0 + rr;
        // stage the input row into LDS (coalesced float4) -> makes in==out safe
        if (tid < 64) {
            reinterpret_cast<float4*>(row)[tid] =
                reinterpret_cast<const float4*>(in + r * 256)[tid];
        }
        __syncthreads();

        const float4* hr = reinterpret_cast<const float4*>(row + c * 64);
        float ax = 0.f, ay = 0.f;
#pragma unroll
        for (int i4 = 0; i4 < 16; ++i4) {
            float4 h4 = hr[i4];
            ax = fmaf(h4.x, w[4 * i4 + 0], ax);
            ay = fmaf(h4.y, w[4 * i4 + 1], ay);
            ax = fmaf(h4.z, w[4 * i4 + 2], ax);
            ay = fmaf(h4.w, w[4 * i4 + 3], ay);
        }
        float p = ax + ay;
        p += __shfl_xor(p, 1, 64);
        p += __shfl_xor(p, 2, 64);
        __syncthreads();  // all LDS reads of `row` done before next stage
        if (c == 0) out[r * 256 + j] = p + bj;
    }
}

__global__ __launch_bounds__(1024) void scan_kernel(
    const float* __restrict__ W,       // [512,256]; recurrent rows [wrow, wrow+256)
    const float* __restrict__ h_init,  // [B,256] initial hidden for this layer
    float* __restrict__ io,            // [B,T,256] in: proj rows, out: h_t rows
    float* __restrict__ hfinal,        // nullptr or [B,256]
    int wrow)
{
    __shared__ float hbuf[2][256];
    const int tid = threadIdx.x;
    const int c = tid & 3;
    const int j = tid >> 2;
    const int b = blockIdx.x;

    float w[64];
#pragma unroll
    for (int i = 0; i < 64; ++i)
        w[i] = W[(size_t)(wrow + c * 64 + i) * 256 + j];

    if (tid < 256) hbuf[0][tid] = h_init[b * 256 + tid];
    __syncthreads();

    float* iob = io + (size_t)b * TT * 256;
    float xp = iob[j];  // proj row for t=0

    for (int t = 0; t < TT; ++t) {
        // prefetch next step's proj row early (hidden under the FMA loop)
        float xp_next = 0.f;
        if (t + 1 < TT) xp_next = iob[(size_t)(t + 1) * 256 + j];

        const float4* hr = reinterpret_cast<const float4*>(&hbuf[t & 1][c * 64]);
        float ax = 0.f, ay = 0.f;
#pragma unroll
        for (int i4 = 0; i4 < 16; ++i4) {
            float4 h4 = hr[i4];
            ax = fmaf(h4.x, w[4 * i4 + 0], ax);
            ay = fmaf(h4.y, w[4 * i4 + 1], ay);
            ax = fmaf(h4.z, w[4 * i4 + 2], ax);
            ay = fmaf(h4.w, w[4 * i4 + 3], ay);
        }
        float p = ax + ay;
        p += __shfl_xor(p, 1, 64);
        p += __shfl_xor(p, 2, 64);

        const float z = p + xp;
        // tanh(z) = 1 - 2/(exp(2z)+1)  (overflow-safe: exp->inf gives 1)
        const float e = __expf(2.0f * z);
        const float h_new = 1.0f - 2.0f / (e + 1.0f);

        if (c == 0) {
            hbuf[(t + 1) & 1][j] = h_new;
            iob[(size_t)t * 256 + j] = h_new;
            if (hfinal && t == TT - 1) hfinal[b * 256 + j] = h_new;
        }
        xp = xp_next;
        __syncthreads();
    }
}

extern "C" void kernel_launch(void* const* d_in, const int* in_sizes, int n_in,
                              void* d_out, int out_size, void* d_ws, size_t ws_size,
                              hipStream_t stream) {
    const float* x  = (const float*)d_in[0];  // [B,T,E]
    const float* h0 = (const float*)d_in[1];  // [L,B,H]
    const float* W0 = (const float*)d_in[2];  // [512,256]
    const float* b0 = (const float*)d_in[3];  // [256]
    const float* W1 = (const float*)d_in[4];  // [512,256]
    const float* b1 = (const float*)d_in[5];  // [256]
    float* out = (float*)d_out;               // [B*T*H] hidden_states + [B*H] ht

    const int R = BB * TT;             // 65536 rows
    const int NWG = 256;
    const int rows_per_wg = R / NWG;   // 256

    // A: xproj0 -> out
    proj_kernel<<<NWG, 1024, 0, stream>>>(x, W0, b0, out, rows_per_wg, 0);
    // B: layer-0 scan in-place (out becomes h0_all)
    scan_kernel<<<BB, 1024, 0, stream>>>(W0, h0 + 0 * BB * HHH, out, nullptr, 256);
    // C: xproj1 in-place (out becomes xproj1)
    proj_kernel<<<NWG, 1024, 0, stream>>>(out, W1, b1, out, rows_per_wg, 0);
    // D: layer-1 scan in-place (out becomes hidden_states) + final ht
    scan_kernel<<<BB, 1024, 0, stream>>>(W1, h0 + 1 * BB * HHH, out,
                                         out + (size_t)BB * TT * HHH, 256);
}

// Round 2
// 5086.837 us; speedup vs baseline: 1.8190x; 1.8190x over previous
//
#include <hip/hip_runtime.h>

// RNN: B=32, T=2048, E=256, H=256, L=2, f32.
//   A: xproj0 = x @ W0[0:256] + b0            -> d_out
//   B: layer-0 scan in-place on d_out
//   C: xproj1 = h0_all @ W1[0:256] + b1       (in-place, double-buffered LDS rows)
//   D: layer-1 scan in-place -> hidden_states; tail: ht
//
// Core pattern (both kernels): 512 threads. tid -> p=tid&3 (quad pos),
// q=tid>>2, c=q&1 (i-half), j=(q>>1)*4+p (output col). Lane holds 128 weights
// W[128c+i][j] in VGPRs. Per 16-wide i-block: each lane does ONE ds_read_b128
// (quad collectively holds 16 h values), then 16 v_fmac_f32 whose h operand is
// a DPP quad_perm broadcast from the owning lane — no LDS re-reads, no bank
// conflicts. 2-way partial reduced via shfl_xor(4).

#define TT 2048
#define BB 32

template <int S>
__device__ __forceinline__ float qb(float x) {
    constexpr int ctrl = S | (S << 2) | (S << 4) | (S << 6);  // quad_perm broadcast S
    int r = __builtin_amdgcn_update_dpp(0, __float_as_int(x), ctrl, 0xF, 0xF, true);
    return __int_as_float(r);
}

// 16 FMAs for one 16-wide i-block starting at weight index base (base = 16*k)
#define QBLOCK(S)                                                  \
    a0 = fmaf(qb<S>(v.x), w[base + 4 * S + 0], a0);                \
    a1 = fmaf(qb<S>(v.y), w[base + 4 * S + 1], a1);                \
    a2 = fmaf(qb<S>(v.z), w[base + 4 * S + 2], a2);                \
    a3 = fmaf(qb<S>(v.w), w[base + 4 * S + 3], a3);

__global__ __launch_bounds__(512) void proj2_kernel(
    const float* in,                  // [R,256] (may alias out)
    const float* __restrict__ W,      // [512,256]; uses rows [0,256)
    const float* __restrict__ bias,   // [256]
    float* out,                       // [R,256]
    int rows_per_wg)
{
    __shared__ float rb[2][256];
    const int tid = threadIdx.x;
    const int p = tid & 3;
    const int q = tid >> 2;
    const int c = q & 1;
    const int j = (q >> 1) * 4 + p;

    float w[128];
#pragma unroll
    for (int i = 0; i < 128; ++i)
        w[i] = W[(size_t)(c * 128 + i) * 256 + j];
    const float bj = bias[j];

    const size_t r0 = (size_t)blockIdx.x * rows_per_wg;

    // stage row 0
    if (tid < 64)
        reinterpret_cast<float4*>(rb[0])[tid] =
            reinterpret_cast<const float4*>(in + r0 * 256)[tid];
    __syncthreads();

    for (int rr = 0; rr < rows_per_wg; ++rr) {
        const int buf = rr & 1;
        // stage next row into the other buffer (read happens before any write
        // of row rr below, so in==out aliasing is safe)
        if (rr + 1 < rows_per_wg && tid < 64)
            reinterpret_cast<float4*>(rb[buf ^ 1])[tid] =
                reinterpret_cast<const float4*>(in + (r0 + rr + 1) * 256)[tid];

        const float* hb = rb[buf] + 128 * c;
        float a0 = 0.f, a1 = 0.f, a2 = 0.f, a3 = 0.f;
#pragma unroll
        for (int k = 0; k < 8; ++k) {
            const int base = 16 * k;
            float4 v = *reinterpret_cast<const float4*>(hb + base + 4 * p);
            QBLOCK(0) QBLOCK(1) QBLOCK(2) QBLOCK(3)
        }
        float t = (a0 + a1) + (a2 + a3);
        t += __shfl_xor(t, 4, 64);
        if (c == 0) out[(r0 + rr) * 256 + j] = t + bj;
        __syncthreads();
    }
}

__global__ __launch_bounds__(512) void scan2_kernel(
    const float* __restrict__ W,       // [512,256]; recurrent rows [256,512)
    const float* __restrict__ h_init,  // [B,256]
    float* __restrict__ io,            // [B,T,256] in: xproj rows, out: h rows
    float* __restrict__ hfinal)        // nullptr or [B,256]
{
    __shared__ float hb2[2][256];
    const int tid = threadIdx.x;
    const int p = tid & 3;
    const int q = tid >> 2;
    const int c = q & 1;
    const int j = (q >> 1) * 4 + p;
    const int b = blockIdx.x;

    float w[128];
#pragma unroll
    for (int i = 0; i < 128; ++i)
        w[i] = W[(size_t)(256 + c * 128 + i) * 256 + j];

    if (tid < 256) hb2[0][tid] = h_init[b * 256 + tid];
    __syncthreads();

    float* iob = io + (size_t)b * TT * 256;
    float xp = iob[j];

    for (int t = 0; t < TT; ++t) {
        float xp_next = 0.f;
        if (t + 1 < TT) xp_next = iob[(size_t)(t + 1) * 256 + j];

        const float* hb = hb2[t & 1] + 128 * c;
        float a0 = 0.f, a1 = 0.f, a2 = 0.f, a3 = 0.f;
#pragma unroll
        for (int k = 0; k < 8; ++k) {
            const int base = 16 * k;
            float4 v = *reinterpret_cast<const float4*>(hb + base + 4 * p);
            QBLOCK(0) QBLOCK(1) QBLOCK(2) QBLOCK(3)
        }
        float s = (a0 + a1) + (a2 + a3);
        s += __shfl_xor(s, 4, 64);

        const float z = s + xp;
        const float e = __expf(2.0f * z);
        const float h_new = 1.0f - 2.0f / (e + 1.0f);

        if (c == 0) {
            hb2[(t + 1) & 1][j] = h_new;
            iob[(size_t)t * 256 + j] = h_new;
            if (hfinal && t == TT - 1) hfinal[b * 256 + j] = h_new;
        }
        xp = xp_next;
        __syncthreads();
    }
}

extern "C" void kernel_launch(void* const* d_in, const int* in_sizes, int n_in,
                              void* d_out, int out_size, void* d_ws, size_t ws_size,
                              hipStream_t stream) {
    const float* x  = (const float*)d_in[0];  // [B,T,256]
    const float* h0 = (const float*)d_in[1];  // [2,B,256]
    const float* W0 = (const float*)d_in[2];  // [512,256]
    const float* b0 = (const float*)d_in[3];  // [256]
    const float* W1 = (const float*)d_in[4];  // [512,256]
    const float* b1 = (const float*)d_in[5];  // [256]
    float* out = (float*)d_out;               // [B*T*256] + [B*256]

    const int R = BB * TT;            // 65536
    const int NWG = 512;
    const int rows_per_wg = R / NWG;  // 128

    proj2_kernel<<<NWG, 512, 0, stream>>>(x, W0, b0, out, rows_per_wg);
    scan2_kernel<<<BB, 512, 0, stream>>>(W0, h0, out, nullptr);
    proj2_kernel<<<NWG, 512, 0, stream>>>(out, W1, b1, out, rows_per_wg);
    scan2_kernel<<<BB, 512, 0, stream>>>(W1, h0 + BB * 256, out,
                                         out + (size_t)BB * TT * 256);
}